// Round 3
// baseline (343.302 us; speedup 1.0000x reference)
//
#include <hip/hip_runtime.h>
#include <hip/hip_bf16.h>

// ResAttention fused forward: out = (v [B,L,H,D] , attn_map [B,H,L,S]), fp32.
// B=4, L=S=2048, H=16, E=D=64.
// Fast path (needs ws >= 50331648 B):
//   conv_qk: Q (pre-scaled by 1/8*log2e), K -> bf16 [b,h,l,e]
//   conv_v : V -> bf16 transposed [b,h,d,s]
//   attn_main: per (b,h,64 q-rows) block, 4 waves, 40 KB LDS -> 4 blocks/CU.
//     phase 1: row sums of exp2(scores), K ring-of-4 LDS buffers, 2-deep
//              prefetch (counted vmcnt(2)).
//     phase 2: recompute scores, write normalized P (float4 nt stores) + PV.
//              K/V double-buffered, vmcnt(4) leaves P stores in flight.
//   Q fragments live in registers (two 16B global loads per lane; no Q LDS).

typedef __attribute__((ext_vector_type(4))) float  f32x4;
typedef __attribute__((ext_vector_type(8))) short  short8;
typedef __attribute__((ext_vector_type(4))) short  short4v;
typedef __attribute__((ext_vector_type(4))) unsigned short u16x4;

__device__ __forceinline__ unsigned short bf(float x) {
  return __builtin_bit_cast(unsigned short, __float2bfloat16(x));
}

__device__ __forceinline__ unsigned short f2bf(float f) {
  unsigned int u = __builtin_bit_cast(unsigned int, f);
  return (unsigned short)((u + 0x7FFFu + ((u >> 16) & 1u)) >> 16);  // RNE
}

#define MFMA16(A, Bv, C) __builtin_amdgcn_mfma_f32_16x16x32_bf16(A, Bv, C, 0, 0, 0)

// ============================ prologue kernels ============================

__global__ __launch_bounds__(256) void conv_qk(const float* __restrict__ Q,
                                               const float* __restrict__ K,
                                               unsigned short* __restrict__ Qbf,
                                               unsigned short* __restrict__ Kbf) {
  int idx = blockIdx.x * 256 + threadIdx.x;   // 2^21 total
  int isK = idx >> 20;
  int rem = idx & 0xFFFFF;
  int e0 = (rem & 7) << 3;
  int h  = (rem >> 3) & 15;
  int l  = (rem >> 7) & 2047;
  int b  = rem >> 18;
  const float* src = (isK ? K : Q) + (((size_t)(b * 2048 + l)) * 16 + h) * 64 + e0;
  unsigned short* dst = (isK ? Kbf : Qbf) + (((size_t)(b * 16 + h)) * 2048 + l) * 64 + e0;
  float sc = isK ? 1.0f : 0.18033688011112042f;  // (1/sqrt(64))*log2(e)
  float4 a = *(const float4*)src;
  float4 c = *(const float4*)(src + 4);
  u16x4 o0 = { bf(a.x * sc), bf(a.y * sc), bf(a.z * sc), bf(a.w * sc) };
  u16x4 o1 = { bf(c.x * sc), bf(c.y * sc), bf(c.z * sc), bf(c.w * sc) };
  *(u16x4*)dst = o0;
  *(u16x4*)(dst + 4) = o1;
}

__global__ __launch_bounds__(256) void conv_v(const float* __restrict__ V,
                                              unsigned short* __restrict__ VT) {
  int bid = blockIdx.x;            // (b*16+h)*32 + sc
  int sc = bid & 31, bh = bid >> 5;
  int h = bh & 15, b = bh >> 4;
  __shared__ unsigned short T[64][68];
  int t = threadIdx.x;
  int srow = t >> 2, d0 = (t & 3) << 4;
  const float* src = V + (((size_t)(b * 2048 + sc * 64 + srow)) * 16 + h) * 64 + d0;
  float4 v0 = *(const float4*)(src + 0);
  float4 v1 = *(const float4*)(src + 4);
  float4 v2 = *(const float4*)(src + 8);
  float4 v3 = *(const float4*)(src + 12);
  T[d0+ 0][srow]=bf(v0.x); T[d0+ 1][srow]=bf(v0.y); T[d0+ 2][srow]=bf(v0.z); T[d0+ 3][srow]=bf(v0.w);
  T[d0+ 4][srow]=bf(v1.x); T[d0+ 5][srow]=bf(v1.y); T[d0+ 6][srow]=bf(v1.z); T[d0+ 7][srow]=bf(v1.w);
  T[d0+ 8][srow]=bf(v2.x); T[d0+ 9][srow]=bf(v2.y); T[d0+10][srow]=bf(v2.z); T[d0+11][srow]=bf(v2.w);
  T[d0+12][srow]=bf(v3.x); T[d0+13][srow]=bf(v3.y); T[d0+14][srow]=bf(v3.z); T[d0+15][srow]=bf(v3.w);
  __syncthreads();
  int d = t >> 2, s0 = (t & 3) << 4;
  unsigned short* dst = VT + ((size_t)bh * 64 + d) * 2048 + sc * 64 + s0;
#pragma unroll
  for (int j = 0; j < 16; j += 4) {
    u16x4 x = { T[d][s0 + j], T[d][s0 + j + 1], T[d][s0 + j + 2], T[d][s0 + j + 3] };
    *(u16x4*)(dst + j) = x;
  }
}

// ============================ main kernel ============================

__device__ __forceinline__ void gll16(const void* g, void* l) {
  __builtin_amdgcn_global_load_lds(
      (const __attribute__((address_space(1))) unsigned int*)g,
      (__attribute__((address_space(3))) unsigned int*)l, 16, 0, 0);
}

// Stage 16 rows (this wave's quarter) of a 64x64 bf16 tile into LDS,
// XOR-swizzled via pre-swizzled per-lane global source (linear LDS dest).
__device__ __forceinline__ void stage16(const unsigned short* gsrc, int rowStride,
                                        unsigned short* dstRow0, int lane) {
  int rr = lane >> 3;                     // row within 8-row group (= row&7)
  int cc = ((lane & 7) ^ rr) << 3;        // swizzled source column (elements)
  gll16(gsrc + (size_t)rr * rowStride + cc,       dstRow0);
  gll16(gsrc + (size_t)(8 + rr) * rowStride + cc, dstRow0 + 8 * 64);
}

// Swizzled b128 fragment read: data column colb (bytes) of tile row `row`.
__device__ __forceinline__ short8 frag(const unsigned short* tile, int row, int colb) {
  return *(const short8*)((const char*)tile + row * 128 + (colb ^ ((row & 7) << 4)));
}

__global__ __launch_bounds__(256, 4) void attn_main(
    const unsigned short* __restrict__ Qbf, const unsigned short* __restrict__ Kbf,
    const unsigned short* __restrict__ VTbf, float* __restrict__ Og,
    float* __restrict__ Ag) {

  // bijective XCD swizzle: 2048 = 8 * 256
  int wg = ((blockIdx.x & 7) << 8) | (blockIdx.x >> 3);
  int qt = wg & 31, bh = wg >> 5;
  int h = bh & 15, b = bh >> 4;

  int tid = threadIdx.x, lane = tid & 63, w = tid >> 6;
  int g = lane >> 4, r16 = lane & 15;

  // 40 KB total -> 4 blocks/CU.
  __shared__ __align__(16) unsigned short SM[4][64][64];   // K ring (ph1) / K[2]+V[2] (ph2)
  __shared__ __align__(16) unsigned short Pb[4][16][64];   // swizzled P tile

  const unsigned short* kg = Kbf + (size_t)bh * 2048 * 64 + (size_t)(w * 16) * 64;
  const unsigned short* vg = VTbf + (size_t)bh * 64 * 2048 + (size_t)(w * 16) * 2048;

  // Q fragment direct from global (L2-hot), kept in registers all kernel.
  const unsigned short* qrow = Qbf + ((size_t)bh * 2048 + qt * 64 + w * 16 + r16) * 64;
  short8 qf0 = *(const short8*)(qrow + g * 8);
  short8 qf1 = *(const short8*)(qrow + 32 + g * 8);
  asm volatile("" : "+v"(qf0), "+v"(qf1));   // materialize before manual vmcnt bookkeeping

  // ---------------- phase 1: row sums, K ring-of-4, 2-deep prefetch ----------------
  stage16(kg, 64, &SM[0][w * 16][0], lane);
  stage16(kg + 4096, 64, &SM[1][w * 16][0], lane);
  asm volatile("s_waitcnt vmcnt(2)" ::: "memory");
  __builtin_amdgcn_s_barrier();

  float lsum = 0.0f;
  for (int ch = 0; ch < 32; ++ch) {
    if (ch < 30)
      stage16(kg + (size_t)(ch + 2) * 4096, 64, &SM[(ch + 2) & 3][w * 16][0], lane);
    const unsigned short* kt = &SM[ch & 3][0][0];
    f32x4 st[4];
    __builtin_amdgcn_s_setprio(1);
#pragma unroll
    for (int t = 0; t < 4; ++t) {
      short8 kf0 = frag(kt, t * 16 + r16, g * 16);
      short8 kf1 = frag(kt, t * 16 + r16, 64 + g * 16);
      f32x4 z = {0.f, 0.f, 0.f, 0.f};
      z = MFMA16(kf0, qf0, z);      // swapped: A=K (s rows), B=Q (q cols)
      z = MFMA16(kf1, qf1, z);
      st[t] = z;
    }
    __builtin_amdgcn_s_setprio(0);
#pragma unroll
    for (int t = 0; t < 4; ++t)
#pragma unroll
      for (int r = 0; r < 4; ++r)
        lsum += __builtin_amdgcn_exp2f(st[t][r]);
    if (ch < 30) {
      asm volatile("s_waitcnt vmcnt(2)" ::: "memory");
    } else {
      asm volatile("s_waitcnt vmcnt(0)" ::: "memory");
    }
    __builtin_amdgcn_s_barrier();
  }
  lsum += __shfl_xor(lsum, 16, 64);
  lsum += __shfl_xor(lsum, 32, 64);
  float rinv = 1.0f / lsum;          // per-lane q = qt*64 + w*16 + r16

  // ---------------- phase 2: P write + PV ----------------
  f32x4 oacc[4];
#pragma unroll
  for (int t = 0; t < 4; ++t) oacc[t] = (f32x4){0.f, 0.f, 0.f, 0.f};

  stage16(kg, 64, &SM[0][w * 16][0], lane);
  stage16(vg, 2048, &SM[2][w * 16][0], lane);
  asm volatile("s_waitcnt vmcnt(0)" ::: "memory");
  __builtin_amdgcn_s_barrier();

  float* aQ = Ag + ((size_t)bh * 2048 + (size_t)(qt * 64 + w * 16 + r16)) * 2048;
  char* prow = (char*)&Pb[w][r16][0];
  const int psw = (r16 & 7) << 4;    // 16B-granular XOR swizzle per q-row

  for (int ch = 0; ch < 32; ++ch) {
    int cur = ch & 1;
    if (ch < 31) {
      stage16(kg + (size_t)(ch + 1) * 4096, 64, &SM[cur ^ 1][w * 16][0], lane);
      stage16(vg + (size_t)(ch + 1) * 64, 2048, &SM[2 + (cur ^ 1)][w * 16][0], lane);
    }
    const unsigned short* kt = &SM[cur][0][0];
    const unsigned short* vt = &SM[2 + cur][0][0];
    f32x4 st[4];
    __builtin_amdgcn_s_setprio(1);
#pragma unroll
    for (int t = 0; t < 4; ++t) {
      short8 kf0 = frag(kt, t * 16 + r16, g * 16);
      short8 kf1 = frag(kt, t * 16 + r16, 64 + g * 16);
      f32x4 z = {0.f, 0.f, 0.f, 0.f};
      z = MFMA16(kf0, qf0, z);
      z = MFMA16(kf1, qf1, z);
      st[t] = z;
    }
    __builtin_amdgcn_s_setprio(0);

    // lane holds P[s = ch*64 + t*16 + 4g + r][q = r16]: s-contiguous in r.
#pragma unroll
    for (int t = 0; t < 4; ++t) {
      f32x4 p;
#pragma unroll
      for (int r = 0; r < 4; ++r)
        p[r] = __builtin_amdgcn_exp2f(st[t][r]) * rinv;
      __builtin_nontemporal_store(p, (f32x4*)(aQ + ch * 64 + t * 16 + 4 * g));
      u16x4 pb = { bf(p[0]), bf(p[1]), bf(p[2]), bf(p[3]) };
      *(u16x4*)(prow + (((t * 32 + g * 8)) ^ psw)) = pb;
    }

    __builtin_amdgcn_s_setprio(1);
#pragma unroll
    for (int c = 0; c < 2; ++c) {
      short8 pa = *(const short8*)(prow + ((c * 64 + g * 16) ^ psw));
#pragma unroll
      for (int t = 0; t < 4; ++t) {
        short8 vf = frag(vt, t * 16 + r16, c * 64 + g * 16);
        oacc[t] = MFMA16(pa, vf, oacc[t]);
      }
    }
    __builtin_amdgcn_s_setprio(0);

    if (ch < 31) {
      // wait only the 4 global_load_lds (oldest); leave nt stores in flight
      asm volatile("s_waitcnt vmcnt(4)" ::: "memory");
      __builtin_amdgcn_s_barrier();
    }
  }

  // v out: [b, l, h, d]; lane (g,r16) holds rows q=4g+r, col d=t*16+r16
  float* op = Og + (((size_t)b * 2048 + (size_t)(qt * 64 + w * 16 + 4 * g)) * 16 + h) * 64;
#pragma unroll
  for (int t = 0; t < 4; ++t)
#pragma unroll
    for (int r = 0; r < 4; ++r)
      op[(size_t)r * 1024 + t * 16 + r16] = oacc[t][r];
}

// ============================ round-1 fallback ============================

__global__ __launch_bounds__(256, 2) void attn_fused(
    const float* __restrict__ Qg, const float* __restrict__ Kg,
    const float* __restrict__ Vg, float* __restrict__ Og,
    float* __restrict__ Ag) {

  const int qt = blockIdx.x & 31;
  const int bh = blockIdx.x >> 5;
  const int h  = bh & 15;
  const int b  = bh >> 4;

  const int tid  = threadIdx.x;
  const int lane = tid & 63;
  const int w    = tid >> 6;
  const int g    = lane >> 4;
  const int r16  = lane & 15;

  __shared__ __align__(16) unsigned short Qbuf[64][72];
  __shared__ __align__(16) unsigned short Kbuf[64][72];
  __shared__ __align__(16) unsigned short VT[64][68];
  __shared__ __align__(16) unsigned short Pbuf[4][16][72];

  const size_t inbase = (size_t)b * (2048u * 1024u) + (size_t)h * 64u;
  const int q0 = qt << 6;

  const int srow = tid >> 2;
  const int sd0  = (tid & 3) << 4;

  {
    const float sc = 0.18033688011112042f;
    const float* gp = Qg + inbase + (size_t)(q0 + srow) * 1024u + sd0;
    float4 va = *(const float4*)(gp + 0);
    float4 vb = *(const float4*)(gp + 4);
    float4 vc = *(const float4*)(gp + 8);
    float4 vd = *(const float4*)(gp + 12);
    unsigned short* dst = &Qbuf[srow][sd0];
    dst[0]=f2bf(va.x*sc); dst[1]=f2bf(va.y*sc); dst[2]=f2bf(va.z*sc); dst[3]=f2bf(va.w*sc);
    dst[4]=f2bf(vb.x*sc); dst[5]=f2bf(vb.y*sc); dst[6]=f2bf(vb.z*sc); dst[7]=f2bf(vb.w*sc);
    dst[8]=f2bf(vc.x*sc); dst[9]=f2bf(vc.y*sc); dst[10]=f2bf(vc.z*sc); dst[11]=f2bf(vc.w*sc);
    dst[12]=f2bf(vd.x*sc); dst[13]=f2bf(vd.y*sc); dst[14]=f2bf(vd.z*sc); dst[15]=f2bf(vd.w*sc);
  }
  __syncthreads();

  const short8 qf0 = *(const short8*)&Qbuf[w*16 + r16][g*8];
  const short8 qf1 = *(const short8*)&Qbuf[w*16 + r16][32 + g*8];

  f32x4 mrow = { -3e38f, -3e38f, -3e38f, -3e38f };
  f32x4 lrow = { 0.f, 0.f, 0.f, 0.f };

  for (int ch = 0; ch < 32; ++ch) {
    __syncthreads();
    {
      const float* gp = Kg + inbase + (size_t)(ch*64 + srow) * 1024u + sd0;
      float4 va = *(const float4*)(gp + 0);
      float4 vb = *(const float4*)(gp + 4);
      float4 vc = *(const float4*)(gp + 8);
      float4 vd = *(const float4*)(gp + 12);
      unsigned short* dst = &Kbuf[srow][sd0];
      dst[0]=f2bf(va.x); dst[1]=f2bf(va.y); dst[2]=f2bf(va.z); dst[3]=f2bf(va.w);
      dst[4]=f2bf(vb.x); dst[5]=f2bf(vb.y); dst[6]=f2bf(vb.z); dst[7]=f2bf(vb.w);
      dst[8]=f2bf(vc.x); dst[9]=f2bf(vc.y); dst[10]=f2bf(vc.z); dst[11]=f2bf(vc.w);
      dst[12]=f2bf(vd.x); dst[13]=f2bf(vd.y); dst[14]=f2bf(vd.z); dst[15]=f2bf(vd.w);
    }
    __syncthreads();

    f32x4 st[4];
#pragma unroll
    for (int t = 0; t < 4; ++t) {
      const short8 kf0 = *(const short8*)&Kbuf[t*16 + r16][g*8];
      const short8 kf1 = *(const short8*)&Kbuf[t*16 + r16][32 + g*8];
      f32x4 z = {0.f, 0.f, 0.f, 0.f};
      z = MFMA16(qf0, kf0, z);
      z = MFMA16(qf1, kf1, z);
      st[t] = z;
    }

    f32x4 cm = st[0];
#pragma unroll
    for (int t = 1; t < 4; ++t)
#pragma unroll
      for (int r = 0; r < 4; ++r) cm[r] = fmaxf(cm[r], st[t][r]);
#pragma unroll
    for (int i = 1; i < 16; i <<= 1)
#pragma unroll
      for (int r = 0; r < 4; ++r) cm[r] = fmaxf(cm[r], __shfl_xor(cm[r], i, 64));

    f32x4 mn, corr, sum = {0.f, 0.f, 0.f, 0.f};
#pragma unroll
    for (int r = 0; r < 4; ++r) {
      mn[r]   = fmaxf(mrow[r], cm[r]);
      corr[r] = exp2f(mrow[r] - mn[r]);
    }
#pragma unroll
    for (int t = 0; t < 4; ++t)
#pragma unroll
      for (int r = 0; r < 4; ++r) sum[r] += exp2f(st[t][r] - mn[r]);
#pragma unroll
    for (int i = 1; i < 16; i <<= 1)
#pragma unroll
      for (int r = 0; r < 4; ++r) sum[r] += __shfl_xor(sum[r], i, 64);
#pragma unroll
    for (int r = 0; r < 4; ++r) {
      lrow[r] = lrow[r] * corr[r] + sum[r];
      mrow[r] = mn[r];
    }
  }

  f32x4 rinv;
#pragma unroll
  for (int r = 0; r < 4; ++r) rinv[r] = 1.0f / lrow[r];

  f32x4 oacc[4];
#pragma unroll
  for (int t = 0; t < 4; ++t) oacc[t] = (f32x4){0.f, 0.f, 0.f, 0.f};

  float* aRow = Ag + ((size_t)bh * 2048u + (size_t)(q0 + w*16 + 4*g)) * 2048u;

  for (int ch = 0; ch < 32; ++ch) {
    __syncthreads();
    {
      const float* gp = Kg + inbase + (size_t)(ch*64 + srow) * 1024u + sd0;
      float4 va = *(const float4*)(gp + 0);
      float4 vb = *(const float4*)(gp + 4);
      float4 vc = *(const float4*)(gp + 8);
      float4 vd = *(const float4*)(gp + 12);
      unsigned short* dst = &Kbuf[srow][sd0];
      dst[0]=f2bf(va.x); dst[1]=f2bf(va.y); dst[2]=f2bf(va.z); dst[3]=f2bf(va.w);
      dst[4]=f2bf(vb.x); dst[5]=f2bf(vb.y); dst[6]=f2bf(vb.z); dst[7]=f2bf(vb.w);
      dst[8]=f2bf(vc.x); dst[9]=f2bf(vc.y); dst[10]=f2bf(vc.z); dst[11]=f2bf(vc.w);
      dst[12]=f2bf(vd.x); dst[13]=f2bf(vd.y); dst[14]=f2bf(vd.z); dst[15]=f2bf(vd.w);
    }
    {
      const float* gp = Vg + inbase + (size_t)(ch*64 + lane) * 1024u + (size_t)(w*16);
      float4 va = *(const float4*)(gp + 0);
      float4 vb = *(const float4*)(gp + 4);
      float4 vc = *(const float4*)(gp + 8);
      float4 vd = *(const float4*)(gp + 12);
      const int dbase = w * 16;
      VT[dbase+ 0][lane]=f2bf(va.x); VT[dbase+ 1][lane]=f2bf(va.y);
      VT[dbase+ 2][lane]=f2bf(va.z); VT[dbase+ 3][lane]=f2bf(va.w);
      VT[dbase+ 4][lane]=f2bf(vb.x); VT[dbase+ 5][lane]=f2bf(vb.y);
      VT[dbase+ 6][lane]=f2bf(vb.z); VT[dbase+ 7][lane]=f2bf(vb.w);
      VT[dbase+ 8][lane]=f2bf(vc.x); VT[dbase+ 9][lane]=f2bf(vc.y);
      VT[dbase+10][lane]=f2bf(vc.z); VT[dbase+11][lane]=f2bf(vc.w);
      VT[dbase+12][lane]=f2bf(vd.x); VT[dbase+13][lane]=f2bf(vd.y);
      VT[dbase+14][lane]=f2bf(vd.z); VT[dbase+15][lane]=f2bf(vd.w);
    }
    __syncthreads();

    f32x4 st[4];
#pragma unroll
    for (int t = 0; t < 4; ++t) {
      const short8 kf0 = *(const short8*)&Kbuf[t*16 + r16][g*8];
      const short8 kf1 = *(const short8*)&Kbuf[t*16 + r16][32 + g*8];
      f32x4 z = {0.f, 0.f, 0.f, 0.f};
      z = MFMA16(qf0, kf0, z);
      z = MFMA16(qf1, kf1, z);
      st[t] = z;
    }

#pragma unroll
    for (int t = 0; t < 4; ++t) {
#pragma unroll
      for (int r = 0; r < 4; ++r) {
        float p = exp2f(st[t][r] - mrow[r]) * rinv[r];
        aRow[(size_t)r * 2048u + (size_t)(ch*64 + t*16 + r16)] = p;
        Pbuf[w][4*g + r][t*16 + r16] = f2bf(p);
      }
    }

#pragma unroll
    for (int c = 0; c < 2; ++c) {
      const short8 pa = *(const short8*)&Pbuf[w][r16][c*32 + g*8];
#pragma unroll
      for (int t = 0; t < 4; ++t) {
        const unsigned short* vp = &VT[t*16 + r16][c*32 + g*8];
        short4v lo = *(const short4v*)vp;
        short4v hi = *(const short4v*)(vp + 4);
        short8 vbf = { lo[0], lo[1], lo[2], lo[3], hi[0], hi[1], hi[2], hi[3] };
        oacc[t] = MFMA16(pa, vbf, oacc[t]);
      }
    }
  }

  float* op = Og + (((size_t)b * 2048u + (size_t)(q0 + w*16 + 4*g)) * 16u + (size_t)h) * 64u;
#pragma unroll
  for (int t = 0; t < 4; ++t)
#pragma unroll
    for (int r = 0; r < 4; ++r)
      op[(size_t)r * 1024u + (size_t)(t*16 + r16)] = oacc[t][r];
}

// ============================ launcher ============================

extern "C" void kernel_launch(void* const* d_in, const int* in_sizes, int n_in,
                              void* d_out, int out_size, void* d_ws, size_t ws_size,
                              hipStream_t stream) {
  const float* Q = (const float*)d_in[0];
  const float* K = (const float*)d_in[1];
  const float* V = (const float*)d_in[2];
  float* Og = (float*)d_out;               // v: 4*2048*16*64 = 8388608
  float* Ag = (float*)d_out + 8388608;     // attn_map: 4*16*2048*2048

  const size_t NEED = 3ull * 8388608ull * 2ull;  // Qbf + Kbf + VTbf = 50331648 B
  if (ws_size >= NEED) {
    unsigned short* Qbf  = (unsigned short*)d_ws;
    unsigned short* Kbf  = Qbf + 8388608;
    unsigned short* VTbf = Kbf + 8388608;
    conv_qk<<<dim3(8192), dim3(256), 0, stream>>>(Q, K, Qbf, Kbf);
    conv_v <<<dim3(2048), dim3(256), 0, stream>>>(V, VTbf);
    attn_main<<<dim3(2048), dim3(256), 0, stream>>>(Qbf, Kbf, VTbf, Og, Ag);
  } else {
    attn_fused<<<dim3(2048), dim3(256), 0, stream>>>(Q, K, V, Og, Ag);
  }
}

// Round 4
// 321.326 us; speedup vs baseline: 1.0684x; 1.0684x over previous
//
#include <hip/hip_runtime.h>
#include <hip/hip_bf16.h>

// ResAttention fused forward: out = (v [B,L,H,D] , attn_map [B,H,L,S]), fp32.
// B=4, L=S=2048, H=16, E=D=64.
// Fast path (needs ws >= 50331648 B):
//   conv_all: Q (pre-scaled by 1/8*log2e), K -> bf16 [b,h,l,e]; V -> bf16 [b,h,d,s]
//   attn_main: per (b,h,64 q-rows) block, 4 waves, ~49 KB LDS -> 3 blocks/CU.
//     phase 1: row sums of exp2(scores). K staged through a 4-slot ring
//              (Kb[0],Kb[1],Vb[0],Vb[1]), TWO chunks per iteration, counted
//              vmcnt(4) so prefetch stays in flight across barriers.
//     phase 2: recompute scores, write normalized P (float4 nt stores) + PV.
//              K/V double-buffered, vmcnt(4) leaves P stores in flight.
//              (R2-proven structure, unchanged.)

typedef __attribute__((ext_vector_type(4))) float  f32x4;
typedef __attribute__((ext_vector_type(8))) short  short8;
typedef __attribute__((ext_vector_type(4))) short  short4v;
typedef __attribute__((ext_vector_type(4))) unsigned short u16x4;

__device__ __forceinline__ unsigned short bf(float x) {
  return __builtin_bit_cast(unsigned short, __float2bfloat16(x));
}

__device__ __forceinline__ unsigned short f2bf(float f) {
  unsigned int u = __builtin_bit_cast(unsigned int, f);
  return (unsigned short)((u + 0x7FFFu + ((u >> 16) & 1u)) >> 16);  // RNE
}

#define MFMA16(A, Bv, C) __builtin_amdgcn_mfma_f32_16x16x32_bf16(A, Bv, C, 0, 0, 0)

// ============================ prologue kernel ============================

__global__ __launch_bounds__(256) void conv_all(const float* __restrict__ Q,
                                                const float* __restrict__ K,
                                                const float* __restrict__ V,
                                                unsigned short* __restrict__ Qbf,
                                                unsigned short* __restrict__ Kbf,
                                                unsigned short* __restrict__ VTbf) {
  __shared__ unsigned short T[64][68];
  if (blockIdx.x < 8192) {
    int idx = blockIdx.x * 256 + threadIdx.x;   // 2^21 total
    int isK = idx >> 20;
    int rem = idx & 0xFFFFF;
    int e0 = (rem & 7) << 3;
    int h  = (rem >> 3) & 15;
    int l  = (rem >> 7) & 2047;
    int b  = rem >> 18;
    const float* src = (isK ? K : Q) + (((size_t)(b * 2048 + l)) * 16 + h) * 64 + e0;
    unsigned short* dst = (isK ? Kbf : Qbf) + (((size_t)(b * 16 + h)) * 2048 + l) * 64 + e0;
    float sc = isK ? 1.0f : 0.18033688011112042f;  // (1/sqrt(64))*log2(e)
    float4 a = *(const float4*)src;
    float4 c = *(const float4*)(src + 4);
    u16x4 o0 = { bf(a.x * sc), bf(a.y * sc), bf(a.z * sc), bf(a.w * sc) };
    u16x4 o1 = { bf(c.x * sc), bf(c.y * sc), bf(c.z * sc), bf(c.w * sc) };
    *(u16x4*)dst = o0;
    *(u16x4*)(dst + 4) = o1;
  } else {
    int bid = blockIdx.x - 8192;     // (b*16+h)*32 + sc
    int sc = bid & 31, bh = bid >> 5;
    int h = bh & 15, b = bh >> 4;
    int t = threadIdx.x;
    int srow = t >> 2, d0 = (t & 3) << 4;
    const float* src = V + (((size_t)(b * 2048 + sc * 64 + srow)) * 16 + h) * 64 + d0;
    float4 v0 = *(const float4*)(src + 0);
    float4 v1 = *(const float4*)(src + 4);
    float4 v2 = *(const float4*)(src + 8);
    float4 v3 = *(const float4*)(src + 12);
    T[d0+ 0][srow]=bf(v0.x); T[d0+ 1][srow]=bf(v0.y); T[d0+ 2][srow]=bf(v0.z); T[d0+ 3][srow]=bf(v0.w);
    T[d0+ 4][srow]=bf(v1.x); T[d0+ 5][srow]=bf(v1.y); T[d0+ 6][srow]=bf(v1.z); T[d0+ 7][srow]=bf(v1.w);
    T[d0+ 8][srow]=bf(v2.x); T[d0+ 9][srow]=bf(v2.y); T[d0+10][srow]=bf(v2.z); T[d0+11][srow]=bf(v2.w);
    T[d0+12][srow]=bf(v3.x); T[d0+13][srow]=bf(v3.y); T[d0+14][srow]=bf(v3.z); T[d0+15][srow]=bf(v3.w);
    __syncthreads();
    int d = t >> 2, s0 = (t & 3) << 4;
    unsigned short* dst = VTbf + ((size_t)bh * 64 + d) * 2048 + sc * 64 + s0;
#pragma unroll
    for (int j = 0; j < 16; j += 4) {
      u16x4 x = { T[d][s0 + j], T[d][s0 + j + 1], T[d][s0 + j + 2], T[d][s0 + j + 3] };
      *(u16x4*)(dst + j) = x;
    }
  }
}

// ============================ main kernel ============================

__device__ __forceinline__ void gll16(const void* g, void* l) {
  __builtin_amdgcn_global_load_lds(
      (const __attribute__((address_space(1))) unsigned int*)g,
      (__attribute__((address_space(3))) unsigned int*)l, 16, 0, 0);
}

// Stage 16 rows (this wave's quarter) of a 64x64 bf16 tile into LDS,
// XOR-swizzled via pre-swizzled per-lane global source (linear LDS dest).
__device__ __forceinline__ void stage16(const unsigned short* gsrc, int rowStride,
                                        unsigned short* dstRow0, int lane) {
  int rr = lane >> 3;                     // row within 8-row group (= row&7)
  int cc = ((lane & 7) ^ rr) << 3;        // swizzled source column (elements)
  gll16(gsrc + (size_t)rr * rowStride + cc,       dstRow0);
  gll16(gsrc + (size_t)(8 + rr) * rowStride + cc, dstRow0 + 8 * 64);
}

// Swizzled b128 fragment read: data column colb (bytes) of tile row `row`.
__device__ __forceinline__ short8 frag(const unsigned short* tile, int row, int colb) {
  return *(const short8*)((const char*)tile + row * 128 + (colb ^ ((row & 7) << 4)));
}

__global__ __launch_bounds__(256, 3) void attn_main(
    const unsigned short* __restrict__ Qbf, const unsigned short* __restrict__ Kbf,
    const unsigned short* __restrict__ VTbf, float* __restrict__ Og,
    float* __restrict__ Ag) {

  // bijective XCD swizzle: 2048 = 8 * 256
  int wg = ((blockIdx.x & 7) << 8) | (blockIdx.x >> 3);
  int qt = wg & 31, bh = wg >> 5;
  int h = bh & 15, b = bh >> 4;

  int tid = threadIdx.x, lane = tid & 63, w = tid >> 6;
  int g = lane >> 4, r16 = lane & 15;

  __shared__ __align__(16) unsigned short Qb[64][64];
  __shared__ __align__(16) unsigned short Kb[2][64][64];
  __shared__ __align__(16) unsigned short Vb[2][64][64];
  __shared__ __align__(16) unsigned short Pb[4][16][72];

  const unsigned short* qg = Qbf + ((size_t)bh * 2048 + qt * 64 + w * 16) * 64;
  const unsigned short* kg = Kbf + (size_t)bh * 2048 * 64 + (size_t)(w * 16) * 64;
  const unsigned short* vg = VTbf + (size_t)bh * 64 * 2048 + (size_t)(w * 16) * 2048;

  // ---- prologue: Q + first two K-pairs into the 4-slot ring ----
  stage16(qg, 64, &Qb[w * 16][0], lane);                       // 2 loads
  stage16(kg,            64, &Kb[0][w * 16][0], lane);         // pair A: ch 0
  stage16(kg + 4096,     64, &Kb[1][w * 16][0], lane);         //         ch 1
  stage16(kg + 2 * 4096, 64, &Vb[0][w * 16][0], lane);         // pair B: ch 2
  stage16(kg + 3 * 4096, 64, &Vb[1][w * 16][0], lane);         //         ch 3
  asm volatile("s_waitcnt vmcnt(8)" ::: "memory");             // Q done
  __builtin_amdgcn_s_barrier();

  short8 qf0 = frag(&Qb[0][0], w * 16 + r16, g * 16);
  short8 qf1 = frag(&Qb[0][0], w * 16 + r16, 64 + g * 16);

  // ---------------- phase 1: row sums, 2 chunks/iter ----------------
  float lsum = 0.0f;
  for (int ii = 0; ii < 16; ++ii) {
    const int hi = ii & 1;
    const unsigned short* sA = hi ? &Vb[0][0][0] : &Kb[0][0][0];
    const unsigned short* sB = hi ? &Vb[1][0][0] : &Kb[1][0][0];

    if (ii < 15) {
      asm volatile("s_waitcnt vmcnt(4)" ::: "memory");   // this iter's pair ready
    } else {
      asm volatile("s_waitcnt vmcnt(0)" ::: "memory");
    }
    __builtin_amdgcn_s_barrier();

    f32x4 st[8];
    __builtin_amdgcn_s_setprio(1);
#pragma unroll
    for (int t = 0; t < 4; ++t) {
      short8 kf0 = frag(sA, t * 16 + r16, g * 16);
      short8 kf1 = frag(sA, t * 16 + r16, 64 + g * 16);
      f32x4 z = {0.f, 0.f, 0.f, 0.f};
      z = MFMA16(kf0, qf0, z);      // swapped: A=K (s rows), B=Q (q cols)
      z = MFMA16(kf1, qf1, z);
      st[t] = z;
    }
#pragma unroll
    for (int t = 0; t < 4; ++t) {
      short8 kf0 = frag(sB, t * 16 + r16, g * 16);
      short8 kf1 = frag(sB, t * 16 + r16, 64 + g * 16);
      f32x4 z = {0.f, 0.f, 0.f, 0.f};
      z = MFMA16(kf0, qf0, z);
      z = MFMA16(kf1, qf1, z);
      st[t + 4] = z;
    }
    __builtin_amdgcn_s_setprio(0);

    // tree-sum 32 exp2 values, single dependent add into lsum
    float acc = 0.f;
#pragma unroll
    for (int t = 0; t < 8; ++t) {
      float e0 = __builtin_amdgcn_exp2f(st[t][0]) + __builtin_amdgcn_exp2f(st[t][1]);
      float e1 = __builtin_amdgcn_exp2f(st[t][2]) + __builtin_amdgcn_exp2f(st[t][3]);
      acc += e0 + e1;
    }
    lsum += acc;

    __builtin_amdgcn_s_barrier();    // all waves done reading this pair's slots

    if (ii < 14) {
      const unsigned short* nk = kg + (size_t)(2 * ii + 4) * 4096;
      unsigned short* dA = hi ? &Vb[0][w * 16][0] : &Kb[0][w * 16][0];
      unsigned short* dB = hi ? &Vb[1][w * 16][0] : &Kb[1][w * 16][0];
      stage16(nk,        64, dA, lane);
      stage16(nk + 4096, 64, dB, lane);
    }
  }
  lsum += __shfl_xor(lsum, 16, 64);
  lsum += __shfl_xor(lsum, 32, 64);
  float rinv = 1.0f / lsum;          // per-lane q = qt*64 + w*16 + r16

  // ---------------- phase 2: P write + PV (R2 structure) ----------------
  f32x4 oacc[4];
#pragma unroll
  for (int t = 0; t < 4; ++t) oacc[t] = (f32x4){0.f, 0.f, 0.f, 0.f};

  stage16(kg, 64, &Kb[0][w * 16][0], lane);
  stage16(vg, 2048, &Vb[0][w * 16][0], lane);
  asm volatile("s_waitcnt vmcnt(0)" ::: "memory");
  __builtin_amdgcn_s_barrier();
  int cur = 0;

  float* aQ = Ag + ((size_t)bh * 2048 + (size_t)(qt * 64 + w * 16 + r16)) * 2048;

  for (int ch = 0; ch < 32; ++ch) {
    if (ch < 31) {
      stage16(kg + (size_t)(ch + 1) * 4096, 64, &Kb[cur ^ 1][w * 16][0], lane);
      stage16(vg + (size_t)(ch + 1) * 64, 2048, &Vb[cur ^ 1][w * 16][0], lane);
    }
    f32x4 st[4];
    __builtin_amdgcn_s_setprio(1);
#pragma unroll
    for (int t = 0; t < 4; ++t) {
      short8 kf0 = frag(&Kb[cur][0][0], t * 16 + r16, g * 16);
      short8 kf1 = frag(&Kb[cur][0][0], t * 16 + r16, 64 + g * 16);
      f32x4 z = {0.f, 0.f, 0.f, 0.f};
      z = MFMA16(kf0, qf0, z);
      z = MFMA16(kf1, qf1, z);
      st[t] = z;
    }
    __builtin_amdgcn_s_setprio(0);

    // lane holds P[s = ch*64 + t*16 + 4g + r][q = r16]: s-contiguous in r.
#pragma unroll
    for (int t = 0; t < 4; ++t) {
      f32x4 p;
#pragma unroll
      for (int r = 0; r < 4; ++r)
        p[r] = __builtin_amdgcn_exp2f(st[t][r]) * rinv;
      __builtin_nontemporal_store(p, (f32x4*)(aQ + ch * 64 + t * 16 + 4 * g));
      u16x4 pb = { bf(p[0]), bf(p[1]), bf(p[2]), bf(p[3]) };
      *(u16x4*)&Pb[w][r16][t * 16 + 4 * g] = pb;
    }

    __builtin_amdgcn_s_setprio(1);
#pragma unroll
    for (int c = 0; c < 2; ++c) {
      short8 pa = *(const short8*)((const char*)&Pb[w][r16][0] + c * 64 + g * 16);
#pragma unroll
      for (int t = 0; t < 4; ++t) {
        short8 vf = frag(&Vb[cur][0][0], t * 16 + r16, c * 64 + g * 16);
        oacc[t] = MFMA16(pa, vf, oacc[t]);
      }
    }
    __builtin_amdgcn_s_setprio(0);

    // wait only the 4 global_load_lds (oldest); leave the 4 nt stores in flight
    asm volatile("s_waitcnt vmcnt(4)" ::: "memory");
    __builtin_amdgcn_s_barrier();
    cur ^= 1;
  }

  // v out: [b, l, h, d]; lane (g,r16) holds rows q=4g+r, col d=t*16+r16
  float* op = Og + (((size_t)b * 2048 + (size_t)(qt * 64 + w * 16 + 4 * g)) * 16 + h) * 64;
#pragma unroll
  for (int t = 0; t < 4; ++t)
#pragma unroll
    for (int r = 0; r < 4; ++r)
      op[(size_t)r * 1024 + t * 16 + r16] = oacc[t][r];
}

// ============================ fp32 fallback ============================

__global__ __launch_bounds__(256, 2) void attn_fused(
    const float* __restrict__ Qg, const float* __restrict__ Kg,
    const float* __restrict__ Vg, float* __restrict__ Og,
    float* __restrict__ Ag) {

  const int qt = blockIdx.x & 31;
  const int bh = blockIdx.x >> 5;
  const int h  = bh & 15;
  const int b  = bh >> 4;

  const int tid  = threadIdx.x;
  const int lane = tid & 63;
  const int w    = tid >> 6;
  const int g    = lane >> 4;
  const int r16  = lane & 15;

  __shared__ __align__(16) unsigned short Qbuf[64][72];
  __shared__ __align__(16) unsigned short Kbuf[64][72];
  __shared__ __align__(16) unsigned short VT[64][68];
  __shared__ __align__(16) unsigned short Pbuf[4][16][72];

  const size_t inbase = (size_t)b * (2048u * 1024u) + (size_t)h * 64u;
  const int q0 = qt << 6;

  const int srow = tid >> 2;
  const int sd0  = (tid & 3) << 4;

  {
    const float sc = 0.18033688011112042f;
    const float* gp = Qg + inbase + (size_t)(q0 + srow) * 1024u + sd0;
    float4 va = *(const float4*)(gp + 0);
    float4 vb = *(const float4*)(gp + 4);
    float4 vc = *(const float4*)(gp + 8);
    float4 vd = *(const float4*)(gp + 12);
    unsigned short* dst = &Qbuf[srow][sd0];
    dst[0]=f2bf(va.x*sc); dst[1]=f2bf(va.y*sc); dst[2]=f2bf(va.z*sc); dst[3]=f2bf(va.w*sc);
    dst[4]=f2bf(vb.x*sc); dst[5]=f2bf(vb.y*sc); dst[6]=f2bf(vb.z*sc); dst[7]=f2bf(vb.w*sc);
    dst[8]=f2bf(vc.x*sc); dst[9]=f2bf(vc.y*sc); dst[10]=f2bf(vc.z*sc); dst[11]=f2bf(vc.w*sc);
    dst[12]=f2bf(vd.x*sc); dst[13]=f2bf(vd.y*sc); dst[14]=f2bf(vd.z*sc); dst[15]=f2bf(vd.w*sc);
  }
  __syncthreads();

  const short8 qf0 = *(const short8*)&Qbuf[w*16 + r16][g*8];
  const short8 qf1 = *(const short8*)&Qbuf[w*16 + r16][32 + g*8];

  f32x4 mrow = { -3e38f, -3e38f, -3e38f, -3e38f };
  f32x4 lrow = { 0.f, 0.f, 0.f, 0.f };

  for (int ch = 0; ch < 32; ++ch) {
    __syncthreads();
    {
      const float* gp = Kg + inbase + (size_t)(ch*64 + srow) * 1024u + sd0;
      float4 va = *(const float4*)(gp + 0);
      float4 vb = *(const float4*)(gp + 4);
      float4 vc = *(const float4*)(gp + 8);
      float4 vd = *(const float4*)(gp + 12);
      unsigned short* dst = &Kbuf[srow][sd0];
      dst[0]=f2bf(va.x); dst[1]=f2bf(va.y); dst[2]=f2bf(va.z); dst[3]=f2bf(va.w);
      dst[4]=f2bf(vb.x); dst[5]=f2bf(vb.y); dst[6]=f2bf(vb.z); dst[7]=f2bf(vb.w);
      dst[8]=f2bf(vc.x); dst[9]=f2bf(vc.y); dst[10]=f2bf(vc.z); dst[11]=f2bf(vc.w);
      dst[12]=f2bf(vd.x); dst[13]=f2bf(vd.y); dst[14]=f2bf(vd.z); dst[15]=f2bf(vd.w);
    }
    __syncthreads();

    f32x4 st[4];
#pragma unroll
    for (int t = 0; t < 4; ++t) {
      const short8 kf0 = *(const short8*)&Kbuf[t*16 + r16][g*8];
      const short8 kf1 = *(const short8*)&Kbuf[t*16 + r16][32 + g*8];
      f32x4 z = {0.f, 0.f, 0.f, 0.f};
      z = MFMA16(qf0, kf0, z);
      z = MFMA16(qf1, kf1, z);
      st[t] = z;
    }

    f32x4 cm = st[0];
#pragma unroll
    for (int t = 1; t < 4; ++t)
#pragma unroll
      for (int r = 0; r < 4; ++r) cm[r] = fmaxf(cm[r], st[t][r]);
#pragma unroll
    for (int i = 1; i < 16; i <<= 1)
#pragma unroll
      for (int r = 0; r < 4; ++r) cm[r] = fmaxf(cm[r], __shfl_xor(cm[r], i, 64));

    f32x4 mn, corr, sum = {0.f, 0.f, 0.f, 0.f};
#pragma unroll
    for (int r = 0; r < 4; ++r) {
      mn[r]   = fmaxf(mrow[r], cm[r]);
      corr[r] = exp2f(mrow[r] - mn[r]);
    }
#pragma unroll
    for (int t = 0; t < 4; ++t)
#pragma unroll
      for (int r = 0; r < 4; ++r) sum[r] += exp2f(st[t][r] - mn[r]);
#pragma unroll
    for (int i = 1; i < 16; i <<= 1)
#pragma unroll
      for (int r = 0; r < 4; ++r) sum[r] += __shfl_xor(sum[r], i, 64);
#pragma unroll
    for (int r = 0; r < 4; ++r) {
      lrow[r] = lrow[r] * corr[r] + sum[r];
      mrow[r] = mn[r];
    }
  }

  f32x4 rinv;
#pragma unroll
  for (int r = 0; r < 4; ++r) rinv[r] = 1.0f / lrow[r];

  f32x4 oacc[4];
#pragma unroll
  for (int t = 0; t < 4; ++t) oacc[t] = (f32x4){0.f, 0.f, 0.f, 0.f};

  float* aRow = Ag + ((size_t)bh * 2048u + (size_t)(q0 + w*16 + 4*g)) * 2048u;

  for (int ch = 0; ch < 32; ++ch) {
    __syncthreads();
    {
      const float* gp = Kg + inbase + (size_t)(ch*64 + srow) * 1024u + sd0;
      float4 va = *(const float4*)(gp + 0);
      float4 vb = *(const float4*)(gp + 4);
      float4 vc = *(const float4*)(gp + 8);
      float4 vd = *(const float4*)(gp + 12);
      unsigned short* dst = &Kbuf[srow][sd0];
      dst[0]=f2bf(va.x); dst[1]=f2bf(va.y); dst[2]=f2bf(va.z); dst[3]=f2bf(va.w);
      dst[4]=f2bf(vb.x); dst[5]=f2bf(vb.y); dst[6]=f2bf(vb.z); dst[7]=f2bf(vb.w);
      dst[8]=f2bf(vc.x); dst[9]=f2bf(vc.y); dst[10]=f2bf(vc.z); dst[11]=f2bf(vc.w);
      dst[12]=f2bf(vd.x); dst[13]=f2bf(vd.y); dst[14]=f2bf(vd.z); dst[15]=f2bf(vd.w);
    }
    {
      const float* gp = Vg + inbase + (size_t)(ch*64 + lane) * 1024u + (size_t)(w*16);
      float4 va = *(const float4*)(gp + 0);
      float4 vb = *(const float4*)(gp + 4);
      float4 vc = *(const float4*)(gp + 8);
      float4 vd = *(const float4*)(gp + 12);
      const int dbase = w * 16;
      VT[dbase+ 0][lane]=f2bf(va.x); VT[dbase+ 1][lane]=f2bf(va.y);
      VT[dbase+ 2][lane]=f2bf(va.z); VT[dbase+ 3][lane]=f2bf(va.w);
      VT[dbase+ 4][lane]=f2bf(vb.x); VT[dbase+ 5][lane]=f2bf(vb.y);
      VT[dbase+ 6][lane]=f2bf(vb.z); VT[dbase+ 7][lane]=f2bf(vb.w);
      VT[dbase+ 8][lane]=f2bf(vc.x); VT[dbase+ 9][lane]=f2bf(vc.y);
      VT[dbase+10][lane]=f2bf(vc.z); VT[dbase+11][lane]=f2bf(vc.w);
      VT[dbase+12][lane]=f2bf(vd.x); VT[dbase+13][lane]=f2bf(vd.y);
      VT[dbase+14][lane]=f2bf(vd.z); VT[dbase+15][lane]=f2bf(vd.w);
    }
    __syncthreads();

    f32x4 st[4];
#pragma unroll
    for (int t = 0; t < 4; ++t) {
      const short8 kf0 = *(const short8*)&Kbuf[t*16 + r16][g*8];
      const short8 kf1 = *(const short8*)&Kbuf[t*16 + r16][32 + g*8];
      f32x4 z = {0.f, 0.f, 0.f, 0.f};
      z = MFMA16(qf0, kf0, z);
      z = MFMA16(qf1, kf1, z);
      st[t] = z;
    }

#pragma unroll
    for (int t = 0; t < 4; ++t) {
#pragma unroll
      for (int r = 0; r < 4; ++r) {
        float p = exp2f(st[t][r] - mrow[r]) * rinv[r];
        aRow[(size_t)r * 2048u + (size_t)(ch*64 + t*16 + r16)] = p;
        Pbuf[w][4*g + r][t*16 + r16] = f2bf(p);
      }
    }

#pragma unroll
    for (int c = 0; c < 2; ++c) {
      const short8 pa = *(const short8*)&Pbuf[w][r16][c*32 + g*8];
#pragma unroll
      for (int t = 0; t < 4; ++t) {
        const unsigned short* vp = &VT[t*16 + r16][c*32 + g*8];
        short4v lo = *(const short4v*)vp;
        short4v hi = *(const short4v*)(vp + 4);
        short8 vbf = { lo[0], lo[1], lo[2], lo[3], hi[0], hi[1], hi[2], hi[3] };
        oacc[t] = MFMA16(pa, vbf, oacc[t]);
      }
    }
  }

  float* op = Og + (((size_t)b * 2048u + (size_t)(q0 + w*16 + 4*g)) * 16u + (size_t)h) * 64u;
#pragma unroll
  for (int t = 0; t < 4; ++t)
#pragma unroll
    for (int r = 0; r < 4; ++r)
      op[(size_t)r * 1024u + (size_t)(t*16 + r16)] = oacc[t][r];
}

// ============================ launcher ============================

extern "C" void kernel_launch(void* const* d_in, const int* in_sizes, int n_in,
                              void* d_out, int out_size, void* d_ws, size_t ws_size,
                              hipStream_t stream) {
  const float* Q = (const float*)d_in[0];
  const float* K = (const float*)d_in[1];
  const float* V = (const float*)d_in[2];
  float* Og = (float*)d_out;               // v: 4*2048*16*64 = 8388608
  float* Ag = (float*)d_out + 8388608;     // attn_map: 4*16*2048*2048

  const size_t NEED = 3ull * 8388608ull * 2ull;  // Qbf + Kbf + VTbf = 50331648 B
  if (ws_size >= NEED) {
    unsigned short* Qbf  = (unsigned short*)d_ws;
    unsigned short* Kbf  = Qbf + 8388608;
    unsigned short* VTbf = Kbf + 8388608;
    conv_all<<<dim3(10240), dim3(256), 0, stream>>>(Q, K, V, Qbf, Kbf, VTbf);
    attn_main<<<dim3(2048), dim3(256), 0, stream>>>(Qbf, Kbf, VTbf, Og, Ag);
  } else {
    attn_fused<<<dim3(2048), dim3(256), 0, stream>>>(Q, K, V, Og, Ag);
  }
}